// Round 1
// baseline (8267.360 us; speedup 1.0000x reference)
//
#include <hip/hip_runtime.h>
#include <math.h>

#define N_ATOMS 50000
#define N_EDGES 1600000
#define NF 128
#define NRBF 20

__device__ __forceinline__ float ssp(float v) {
    // shifted softplus: log1p(exp(v)) - log(2), numerically stable
    return fmaxf(v, 0.0f) + log1pf(__expf(-fabsf(v))) - 0.69314718055994531f;
}

// C[r][f] = act( sum_k A[r][k] * W[k][f] + (BIAS ? b[f] : 0) ), 128x128 W
template<bool SSP_ACT, bool BIAS>
__global__ __launch_bounds__(128) void rowgemm128(
    const float* __restrict__ A, const float* __restrict__ W,
    const float* __restrict__ bias, float* __restrict__ C, int nrows)
{
    __shared__ float sW[128 * 128];
    __shared__ float sAt[128][8];   // [k][row 0..3], padded to 8 for b128 reads
    const int f = threadIdx.x;
    for (int i = f; i < 128 * 128; i += 128) sW[i] = W[i];
    const float bv = BIAS ? bias[f] : 0.0f;
    const int ngroups = (nrows + 3) >> 2;   // 50000 % 4 == 0
    for (int g = blockIdx.x; g < ngroups; g += gridDim.x) {
        const int row0 = g * 4;
        __syncthreads();
        float4 v;
        v.x = A[(size_t)(row0 + 0) * 128 + f];
        v.y = A[(size_t)(row0 + 1) * 128 + f];
        v.z = A[(size_t)(row0 + 2) * 128 + f];
        v.w = A[(size_t)(row0 + 3) * 128 + f];
        *(float4*)(&sAt[f][0]) = v;
        __syncthreads();
        float acc0 = bv, acc1 = bv, acc2 = bv, acc3 = bv;
        #pragma unroll 8
        for (int k = 0; k < 128; ++k) {
            const float w = sW[k * 128 + f];
            const float4 a = *(const float4*)(&sAt[k][0]);
            acc0 = fmaf(a.x, w, acc0);
            acc1 = fmaf(a.y, w, acc1);
            acc2 = fmaf(a.z, w, acc2);
            acc3 = fmaf(a.w, w, acc3);
        }
        if (SSP_ACT) { acc0 = ssp(acc0); acc1 = ssp(acc1); acc2 = ssp(acc2); acc3 = ssp(acc3); }
        C[(size_t)(row0 + 0) * 128 + f] = acc0;
        C[(size_t)(row0 + 1) * 128 + f] = acc1;
        C[(size_t)(row0 + 2) * 128 + f] = acc2;
        C[(size_t)(row0 + 3) * 128 + f] = acc3;
    }
}

// Fused: filter-network -> rcut scale -> gather h[idx_j] -> modulate -> segment-sum scatter.
// One block = 128 threads, thread f owns feature f. W1/W2 columns live in registers.
__global__ __launch_bounds__(128, 2) void edge_kernel(
    const float* __restrict__ f_ij, const float* __restrict__ rcut,
    const int* __restrict__ idx_i, const int* __restrict__ idx_j,
    const float* __restrict__ h,
    const float* __restrict__ W1, const float* __restrict__ b1,
    const float* __restrict__ W2, const float* __restrict__ b2,
    float* __restrict__ y)
{
    __shared__ float sT[2][128];
    const int f = threadIdx.x;

    float w1r[NRBF];
    #pragma unroll
    for (int k = 0; k < NRBF; ++k) w1r[k] = W1[k * 128 + f];
    float w2r[128];
    #pragma unroll
    for (int k = 0; k < 128; ++k) w2r[k] = W2[k * 128 + f];
    const float b1v = b1[f];
    const float b2v = b2[f];

    const int per = (N_EDGES + gridDim.x - 1) / gridDim.x;
    const int e0 = blockIdx.x * per;
    const int e1 = min(e0 + per, N_EDGES);
    if (e0 >= e1) return;   // whole block exits together

    int cur = idx_i[e0];
    float acc = 0.0f;
    int p = 0;
    for (int e = e0; e < e1; ++e) {
        // layer 1: t = ssp(f_ij[e] @ W1 + b1)  (f_ij row read as 5 broadcast float4s)
        const float4* fr = (const float4*)(f_ij + (size_t)e * NRBF);
        float4 q[5];
        #pragma unroll
        for (int u = 0; u < 5; ++u) q[u] = fr[u];
        float pre = b1v;
        #pragma unroll
        for (int u = 0; u < 5; ++u) {
            pre = fmaf(q[u].x, w1r[4 * u + 0], pre);
            pre = fmaf(q[u].y, w1r[4 * u + 1], pre);
            pre = fmaf(q[u].z, w1r[4 * u + 2], pre);
            pre = fmaf(q[u].w, w1r[4 * u + 3], pre);
        }
        sT[p][f] = ssp(pre);
        __syncthreads();   // single barrier per edge; parity buffer protects WAR

        // layer 2: w = t @ W2 + b2 (t broadcast from LDS, W2 column in regs)
        float acc2 = b2v;
        #pragma unroll
        for (int k0 = 0; k0 < 128; k0 += 4) {
            const float4 tq = *(const float4*)(&sT[p][k0]);
            acc2 = fmaf(tq.x, w2r[k0 + 0], acc2);
            acc2 = fmaf(tq.y, w2r[k0 + 1], acc2);
            acc2 = fmaf(tq.z, w2r[k0 + 2], acc2);
            acc2 = fmaf(tq.w, w2r[k0 + 3], acc2);
        }
        const float wij = acc2 * rcut[e];
        const int j = idx_j[e];
        const float xij = h[(size_t)j * 128 + f] * wij;
        const int i = idx_i[e];
        if (i != cur) {   // uniform across block (i depends only on e)
            atomicAdd(&y[(size_t)cur * 128 + f], acc);
            acc = 0.0f;
            cur = i;
        }
        acc += xij;
        p ^= 1;
    }
    atomicAdd(&y[(size_t)cur * 128 + f], acc);
}

extern "C" void kernel_launch(void* const* d_in, const int* in_sizes, int n_in,
                              void* d_out, int out_size, void* d_ws, size_t ws_size,
                              hipStream_t stream) {
    const float* x      = (const float*)d_in[0];
    const float* f_ij   = (const float*)d_in[1];
    const float* rcut   = (const float*)d_in[2];
    const int*   idx_i  = (const int*)d_in[3];
    const int*   idx_j  = (const int*)d_in[4];
    const float* W_in2f = (const float*)d_in[5];
    const float* W_f1   = (const float*)d_in[6];
    const float* b_f1   = (const float*)d_in[7];
    const float* W_f2   = (const float*)d_in[8];
    const float* b_f2   = (const float*)d_in[9];
    const float* W_o1   = (const float*)d_in[10];
    const float* b_o1   = (const float*)d_in[11];
    const float* W_o2   = (const float*)d_in[12];
    const float* b_o2   = (const float*)d_in[13];

    float* out = (float*)d_out;
    float* h   = (float*)d_ws;   // 50000*128 fp32 = 25.6 MB; reused for z after cfconv

    // y accumulates directly in d_out; zero it (harness poisons with 0xAA)
    hipMemsetAsync(out, 0, (size_t)N_ATOMS * NF * sizeof(float), stream);

    // h = x @ W_in2f
    rowgemm128<false, false><<<2048, 128, 0, stream>>>(x, W_in2f, nullptr, h, N_ATOMS);
    // fused filter + cfconv scatter into y (= d_out)
    edge_kernel<<<2048, 128, 0, stream>>>(f_ij, rcut, idx_i, idx_j, h,
                                          W_f1, b_f1, W_f2, b_f2, out);
    // z = ssp(y @ W_o1 + b_o1)  -> reuse h region
    rowgemm128<true, true><<<2048, 128, 0, stream>>>(out, W_o1, b_o1, h, N_ATOMS);
    // out = z @ W_o2 + b_o2
    rowgemm128<false, true><<<2048, 128, 0, stream>>>(h, W_o2, b_o2, out, N_ATOMS);
}

// Round 2
// 1511.651 us; speedup vs baseline: 5.4691x; 5.4691x over previous
//
#include <hip/hip_runtime.h>
#include <math.h>

#define N_ATOMS 50000
#define N_EDGES 1600000
#define NF 128
#define NRBF 20
#define TILE_E 32
#define N_TILES (N_EDGES / TILE_E)   // 50000 exact

typedef __attribute__((ext_vector_type(8))) short bf16x8;
typedef __attribute__((ext_vector_type(4))) float f32x4;

__device__ __forceinline__ float ssp(float v) {
    // shifted softplus: log1p(exp(v)) - log(2), numerically stable
    return fmaxf(v, 0.0f) + log1pf(__expf(-fabsf(v))) - 0.69314718055994531f;
}
__device__ __forceinline__ unsigned short f2bf(float f) {   // fp32 -> bf16 bits, RNE
    unsigned int u = __float_as_uint(f);
    u += 0x7fff + ((u >> 16) & 1);
    return (unsigned short)(u >> 16);
}
__device__ __forceinline__ float bf2f(unsigned short b) {
    return __uint_as_float(((unsigned int)b) << 16);
}

// ---------------------------------------------------------------------------
// C[r][f] = act( sum_k A[r][k] * W[k][f] + (BIAS ? b[f] : 0) ), 128x128 W
template<bool SSP_ACT, bool BIAS>
__global__ __launch_bounds__(128) void rowgemm128(
    const float* __restrict__ A, const float* __restrict__ W,
    const float* __restrict__ bias, float* __restrict__ C, int nrows)
{
    __shared__ float sW[128 * 128];
    __shared__ float sAt[128][8];
    const int f = threadIdx.x;
    for (int i = f; i < 128 * 128; i += 128) sW[i] = W[i];
    const float bv = BIAS ? bias[f] : 0.0f;
    const int ngroups = (nrows + 3) >> 2;
    for (int g = blockIdx.x; g < ngroups; g += gridDim.x) {
        const int row0 = g * 4;
        __syncthreads();
        float4 v;
        v.x = A[(size_t)(row0 + 0) * 128 + f];
        v.y = A[(size_t)(row0 + 1) * 128 + f];
        v.z = A[(size_t)(row0 + 2) * 128 + f];
        v.w = A[(size_t)(row0 + 3) * 128 + f];
        *(float4*)(&sAt[f][0]) = v;
        __syncthreads();
        float acc0 = bv, acc1 = bv, acc2 = bv, acc3 = bv;
        #pragma unroll 8
        for (int k = 0; k < 128; ++k) {
            const float w = sW[k * 128 + f];
            const float4 a = *(const float4*)(&sAt[k][0]);
            acc0 = fmaf(a.x, w, acc0);
            acc1 = fmaf(a.y, w, acc1);
            acc2 = fmaf(a.z, w, acc2);
            acc3 = fmaf(a.w, w, acc3);
        }
        if (SSP_ACT) { acc0 = ssp(acc0); acc1 = ssp(acc1); acc2 = ssp(acc2); acc3 = ssp(acc3); }
        C[(size_t)(row0 + 0) * 128 + f] = acc0;
        C[(size_t)(row0 + 1) * 128 + f] = acc1;
        C[(size_t)(row0 + 2) * 128 + f] = acc2;
        C[(size_t)(row0 + 3) * 128 + f] = acc3;
    }
}

// ---------------------------------------------------------------------------
// Fused edge kernel, MFMA-based, hi/lo bf16 split for fp32-like accuracy.
// Block = 512 threads = 8 waves. Tile = 32 edges.
// Wave w: rhalf = w>>2 (rows rhalf*16..+15), cpair = w&3 (cols cpair*32..+31).
// W1/W2 B-fragments (hi+lo) live in registers per wave, loaded once.
__global__ __launch_bounds__(512, 2) void edge_mfma(
    const float* __restrict__ f_ij, const float* __restrict__ rcut,
    const int* __restrict__ idx_i, const int* __restrict__ idx_j,
    const float* __restrict__ h,
    const float* __restrict__ W1, const float* __restrict__ b1,
    const float* __restrict__ W2, const float* __restrict__ b2,
    float* __restrict__ y)
{
    __shared__ unsigned short sA1H[32][40], sA1L[32][40];   // f_ij tile hi/lo (k padded to 32, row stride 40)
    __shared__ unsigned short sTH[32][136], sTL[32][136];   // t tile hi/lo
    __shared__ float sXij[32][132];                          // xij staging
    __shared__ int   sI[32], sJ[32];
    __shared__ float sRc[32];

    const int tid  = threadIdx.x;
    const int wave = tid >> 6;
    const int lane = tid & 63;
    const int l15  = lane & 15;
    const int quad = lane >> 4;
    const int rhalf = wave >> 2;        // 0/1
    const int cpair = wave & 3;         // 0..3
    const int r0 = rhalf * 16;

    // ---- load weight B-fragments into registers (one-time) ----
    // frag element j of coltile ct holds W[k = kbase + quad*8 + j][c], c = cpair*32+ct*16+l15
    bf16x8 w1h[2], w1l[2];
    bf16x8 w2h[2][4], w2l[2][4];
    float b1r[2], b2r[2];
    #pragma unroll
    for (int ct = 0; ct < 2; ++ct) {
        const int c = cpair * 32 + ct * 16 + l15;
        b1r[ct] = b1[c];
        b2r[ct] = b2[c];
        #pragma unroll
        for (int j = 0; j < 8; ++j) {
            const int k = quad * 8 + j;
            const float v = (k < NRBF) ? W1[k * 128 + c] : 0.0f;
            const unsigned short hb = f2bf(v);
            w1h[ct][j] = (short)hb;
            w1l[ct][j] = (short)f2bf(v - bf2f(hb));
        }
        #pragma unroll
        for (int kk = 0; kk < 4; ++kk) {
            #pragma unroll
            for (int j = 0; j < 8; ++j) {
                const int k = kk * 32 + quad * 8 + j;
                const float v = W2[k * 128 + c];
                const unsigned short hb = f2bf(v);
                w2h[ct][kk][j] = (short)hb;
                w2l[ct][kk][j] = (short)f2bf(v - bf2f(hb));
            }
        }
    }

    // ---- tile range for this block (contiguous edges -> run-carry works) ----
    const int nb = gridDim.x;
    const int t0 = (int)(((long long)blockIdx.x * N_TILES) / nb);
    const int t1 = (int)(((long long)(blockIdx.x + 1) * N_TILES) / nb);

    // per-thread segment run-carry state (sorted idx_i)
    const int col = tid & 127;
    const int qtr = tid >> 7;          // 0..3 -> rows qtr*8..+7 in reduce phase
    int   curI = idx_i[(size_t)t0 * TILE_E];
    float accV = 0.0f;

    for (int t = t0; t < t1; ++t) {
        const int e0 = t * TILE_E;

        // ---- stage f_ij tile (hi/lo), idx/rcut ----
        {
            const int er   = tid >> 4;      // 0..31
            const int slot = tid & 15;
            if (slot < 5) {
                const float4 q = *(const float4*)(f_ij + (size_t)(e0 + er) * NRBF + slot * 4);
                float vals[4] = {q.x, q.y, q.z, q.w};
                #pragma unroll
                for (int u = 0; u < 4; ++u) {
                    const unsigned short hb = f2bf(vals[u]);
                    sA1H[er][slot * 4 + u] = hb;
                    sA1L[er][slot * 4 + u] = f2bf(vals[u] - bf2f(hb));
                }
            } else if (slot < 8) {          // k = 20..31 zero pad
                #pragma unroll
                for (int u = 0; u < 4; ++u) {
                    sA1H[er][slot * 4 + u] = 0;
                    sA1L[er][slot * 4 + u] = 0;
                }
            }
            if (tid < 32) {
                sI[tid]  = idx_i[e0 + tid];
                sJ[tid]  = idx_j[e0 + tid];
                sRc[tid] = rcut[e0 + tid];
            }
        }
        __syncthreads();

        // ---- layer 1: t = ssp(A1 @ W1 + b1), hi/lo MFMA ----
        {
            const bf16x8 ah = *(const bf16x8*)(&sA1H[r0 + l15][quad * 8]);
            const bf16x8 al = *(const bf16x8*)(&sA1L[r0 + l15][quad * 8]);
            #pragma unroll
            for (int ct = 0; ct < 2; ++ct) {
                f32x4 d = {0.0f, 0.0f, 0.0f, 0.0f};
                d = __builtin_amdgcn_mfma_f32_16x16x32_bf16(ah, w1h[ct], d, 0, 0, 0);
                d = __builtin_amdgcn_mfma_f32_16x16x32_bf16(al, w1h[ct], d, 0, 0, 0);
                d = __builtin_amdgcn_mfma_f32_16x16x32_bf16(ah, w1l[ct], d, 0, 0, 0);
                const int c = cpair * 32 + ct * 16 + l15;
                #pragma unroll
                for (int r = 0; r < 4; ++r) {
                    const float tv = ssp(d[r] + b1r[ct]);
                    const unsigned short hb = f2bf(tv);
                    const int row = r0 + quad * 4 + r;
                    sTH[row][c] = hb;
                    sTL[row][c] = f2bf(tv - bf2f(hb));
                }
            }
        }
        __syncthreads();

        // ---- layer 2: Wij = t @ W2 + b2, then xij = h[idx_j] * Wij * rcut ----
        {
            bf16x8 ath[4], atl[4];
            #pragma unroll
            for (int kk = 0; kk < 4; ++kk) {
                ath[kk] = *(const bf16x8*)(&sTH[r0 + l15][kk * 32 + quad * 8]);
                atl[kk] = *(const bf16x8*)(&sTL[r0 + l15][kk * 32 + quad * 8]);
            }
            #pragma unroll
            for (int ct = 0; ct < 2; ++ct) {
                f32x4 acc = {0.0f, 0.0f, 0.0f, 0.0f};
                #pragma unroll
                for (int kk = 0; kk < 4; ++kk) {
                    acc = __builtin_amdgcn_mfma_f32_16x16x32_bf16(ath[kk], w2h[ct][kk], acc, 0, 0, 0);
                    acc = __builtin_amdgcn_mfma_f32_16x16x32_bf16(atl[kk], w2h[ct][kk], acc, 0, 0, 0);
                    acc = __builtin_amdgcn_mfma_f32_16x16x32_bf16(ath[kk], w2l[ct][kk], acc, 0, 0, 0);
                }
                const int c = cpair * 32 + ct * 16 + l15;
                #pragma unroll
                for (int r = 0; r < 4; ++r) {
                    const int row = r0 + quad * 4 + r;
                    const float wij = (acc[r] + b2r[ct]) * sRc[row];
                    const int j = sJ[row];
                    const float hv = h[(size_t)j * 128 + c];
                    sXij[row][c] = wij * hv;
                }
            }
        }
        __syncthreads();

        // ---- segmented reduce over sorted idx_i, run-carry across tiles ----
        #pragma unroll
        for (int r = 0; r < 8; ++r) {
            const int row = qtr * 8 + r;
            const int i = sI[row];                 // uniform per wave
            const float v = sXij[row][col];
            if (i != curI) {
                atomicAdd(&y[(size_t)curI * 128 + col], accV);
                curI = i;
                accV = v;
            } else {
                accV += v;
            }
        }
        __syncthreads();   // protect sI/sJ/sRc/sXij before next tile's staging
    }
    atomicAdd(&y[(size_t)curI * 128 + col], accV);
}

// ---------------------------------------------------------------------------
extern "C" void kernel_launch(void* const* d_in, const int* in_sizes, int n_in,
                              void* d_out, int out_size, void* d_ws, size_t ws_size,
                              hipStream_t stream) {
    const float* x      = (const float*)d_in[0];
    const float* f_ij   = (const float*)d_in[1];
    const float* rcut   = (const float*)d_in[2];
    const int*   idx_i  = (const int*)d_in[3];
    const int*   idx_j  = (const int*)d_in[4];
    const float* W_in2f = (const float*)d_in[5];
    const float* W_f1   = (const float*)d_in[6];
    const float* b_f1   = (const float*)d_in[7];
    const float* W_f2   = (const float*)d_in[8];
    const float* b_f2   = (const float*)d_in[9];
    const float* W_o1   = (const float*)d_in[10];
    const float* b_o1   = (const float*)d_in[11];
    const float* W_o2   = (const float*)d_in[12];
    const float* b_o2   = (const float*)d_in[13];

    float* out = (float*)d_out;
    float* h   = (float*)d_ws;   // 50000*128 fp32 = 25.6 MB; reused for z after cfconv

    // y accumulates directly in d_out; zero it (harness poisons with 0xAA)
    hipMemsetAsync(out, 0, (size_t)N_ATOMS * NF * sizeof(float), stream);

    // h = x @ W_in2f
    rowgemm128<false, false><<<2048, 128, 0, stream>>>(x, W_in2f, nullptr, h, N_ATOMS);
    // fused filter + cfconv scatter into y (= d_out)
    edge_mfma<<<512, 512, 0, stream>>>(f_ij, rcut, idx_i, idx_j, h,
                                       W_f1, b_f1, W_f2, b_f2, out);
    // z = ssp(y @ W_o1 + b_o1)  -> reuse h region
    rowgemm128<true, true><<<2048, 128, 0, stream>>>(out, W_o1, b_o1, h, N_ATOMS);
    // out = z @ W_o2 + b_o2
    rowgemm128<false, true><<<2048, 128, 0, stream>>>(h, W_o2, b_o2, out, N_ATOMS);
}

// Round 3
// 840.059 us; speedup vs baseline: 9.8414x; 1.7995x over previous
//
#include <hip/hip_runtime.h>
#include <math.h>

#define N_ATOMS 50000
#define N_EDGES 1600000
#define NF 128
#define NRBF 20
#define TILE_E 32
#define N_TILES (N_EDGES / TILE_E)   // 50000 exact

typedef __attribute__((ext_vector_type(8))) short bf16x8;
typedef __attribute__((ext_vector_type(4))) float f32x4;

__device__ __forceinline__ float ssp(float v) {
    // shifted softplus via fast exp/log: max(v,0)+log(1+exp(-|v|)) - log2
    return fmaxf(v, 0.0f) + __logf(1.0f + __expf(-fabsf(v))) - 0.69314718055994531f;
}
__device__ __forceinline__ unsigned short f2bf(float f) {   // fp32 -> bf16 bits, RNE
    unsigned int u = __float_as_uint(f);
    u += 0x7fff + ((u >> 16) & 1);
    return (unsigned short)(u >> 16);
}
__device__ __forceinline__ float bf2f(unsigned short b) {
    return __uint_as_float(((unsigned int)b) << 16);
}

// ---------------------------------------------------------------------------
// MFMA row-GEMM: C[r][c] = act( A[r][:128] @ W[:128][c] + b[c] ), hi/lo bf16.
// Block = 512 = 8 waves: rhalf = wave>>2 (16 rows), cpair = wave&3 (32 cols).
// W fragments in registers; A read straight from global; no LDS, no barriers.
template<bool SSP_ACT, bool BIAS>
__global__ __launch_bounds__(512) void rowgemm_mfma(
    const float* __restrict__ A, const float* __restrict__ W,
    const float* __restrict__ bias, float* __restrict__ C, int nrows)
{
    const int tid  = threadIdx.x;
    const int wave = tid >> 6, lane = tid & 63;
    const int l15  = lane & 15, quad = lane >> 4;
    const int rhalf = wave >> 2, cpair = wave & 3;
    const int r0 = rhalf * 16;

    bf16x8 wh[2][4], wl[2][4];
    float br[2];
    #pragma unroll
    for (int ct = 0; ct < 2; ++ct) {
        const int c = cpair * 32 + ct * 16 + l15;
        br[ct] = BIAS ? bias[c] : 0.0f;
        #pragma unroll
        for (int kk = 0; kk < 4; ++kk) {
            #pragma unroll
            for (int j = 0; j < 8; ++j) {
                const int k = kk * 32 + quad * 8 + j;
                const float v = W[k * 128 + c];
                const unsigned short hb = f2bf(v);
                wh[ct][kk][j] = (short)hb;
                wl[ct][kk][j] = (short)f2bf(v - bf2f(hb));
            }
        }
    }

    const int ntiles = (nrows + 31) >> 5;
    for (int t = blockIdx.x; t < ntiles; t += gridDim.x) {
        const int rowbase = t * 32;
        const int arow = rowbase + r0 + l15;
        bf16x8 ah[4], al[4];
        if (arow < nrows) {
            #pragma unroll
            for (int kk = 0; kk < 4; ++kk) {
                const float4 q0 = *(const float4*)(A + (size_t)arow * 128 + kk * 32 + quad * 8);
                const float4 q1 = *(const float4*)(A + (size_t)arow * 128 + kk * 32 + quad * 8 + 4);
                const float vals[8] = {q0.x, q0.y, q0.z, q0.w, q1.x, q1.y, q1.z, q1.w};
                #pragma unroll
                for (int j = 0; j < 8; ++j) {
                    const unsigned short hb = f2bf(vals[j]);
                    ah[kk][j] = (short)hb;
                    al[kk][j] = (short)f2bf(vals[j] - bf2f(hb));
                }
            }
        } else {
            #pragma unroll
            for (int kk = 0; kk < 4; ++kk) {
                #pragma unroll
                for (int j = 0; j < 8; ++j) { ah[kk][j] = 0; al[kk][j] = 0; }
            }
        }
        #pragma unroll
        for (int ct = 0; ct < 2; ++ct) {
            f32x4 acc = {0.0f, 0.0f, 0.0f, 0.0f};
            #pragma unroll
            for (int kk = 0; kk < 4; ++kk) {
                acc = __builtin_amdgcn_mfma_f32_16x16x32_bf16(ah[kk], wh[ct][kk], acc, 0, 0, 0);
                acc = __builtin_amdgcn_mfma_f32_16x16x32_bf16(al[kk], wh[ct][kk], acc, 0, 0, 0);
                acc = __builtin_amdgcn_mfma_f32_16x16x32_bf16(ah[kk], wl[ct][kk], acc, 0, 0, 0);
            }
            const int c = cpair * 32 + ct * 16 + l15;
            #pragma unroll
            for (int r = 0; r < 4; ++r) {
                const int row = rowbase + r0 + quad * 4 + r;
                if (row < nrows) {
                    float v = acc[r] + br[ct];
                    if (SSP_ACT) v = ssp(v);
                    C[(size_t)row * 128 + c] = v;
                }
            }
        }
    }
}

// ---------------------------------------------------------------------------
// Fused edge kernel. Layer-1 hi/lo on f_ij; t stored bf16-hi only (error
// budget analysis: ~1e-2 final absmax vs 0.058 threshold); W2-lo kept in regs.
__global__ __launch_bounds__(512, 2) void edge_mfma(
    const float* __restrict__ f_ij, const float* __restrict__ rcut,
    const int* __restrict__ idx_i, const int* __restrict__ idx_j,
    const float* __restrict__ h,
    const float* __restrict__ W1, const float* __restrict__ b1,
    const float* __restrict__ W2, const float* __restrict__ b2,
    float* __restrict__ y)
{
    __shared__ unsigned short sA1H[32][40], sA1L[32][40];   // f_ij tile hi/lo
    __shared__ unsigned short sTH[32][136];                  // t tile (bf16 hi)
    __shared__ float sXij[32][132];
    __shared__ int   sI[32], sJ[32];
    __shared__ float sRc[32];

    const int tid  = threadIdx.x;
    const int wave = tid >> 6;
    const int lane = tid & 63;
    const int l15  = lane & 15;
    const int quad = lane >> 4;
    const int rhalf = wave >> 2;
    const int cpair = wave & 3;
    const int r0 = rhalf * 16;

    // weight fragments (one-time)
    bf16x8 w1h[2], w1l[2];
    bf16x8 w2h[2][4], w2l[2][4];
    float b1r[2], b2r[2];
    #pragma unroll
    for (int ct = 0; ct < 2; ++ct) {
        const int c = cpair * 32 + ct * 16 + l15;
        b1r[ct] = b1[c];
        b2r[ct] = b2[c];
        #pragma unroll
        for (int j = 0; j < 8; ++j) {
            const int k = quad * 8 + j;
            const float v = (k < NRBF) ? W1[k * 128 + c] : 0.0f;
            const unsigned short hb = f2bf(v);
            w1h[ct][j] = (short)hb;
            w1l[ct][j] = (short)f2bf(v - bf2f(hb));
        }
        #pragma unroll
        for (int kk = 0; kk < 4; ++kk) {
            #pragma unroll
            for (int j = 0; j < 8; ++j) {
                const int k = kk * 32 + quad * 8 + j;
                const float v = W2[k * 128 + c];
                const unsigned short hb = f2bf(v);
                w2h[ct][kk][j] = (short)hb;
                w2l[ct][kk][j] = (short)f2bf(v - bf2f(hb));
            }
        }
    }

    const int nb = gridDim.x;
    const int t0 = (int)(((long long)blockIdx.x * N_TILES) / nb);
    const int t1 = (int)(((long long)(blockIdx.x + 1) * N_TILES) / nb);

    const int col = tid & 127;
    const int qtr = tid >> 7;
    int   curI = idx_i[(size_t)t0 * TILE_E];
    float accV = 0.0f;

    for (int t = t0; t < t1; ++t) {
        const int e0 = t * TILE_E;

        // ---- stage f_ij tile (hi/lo), idx/rcut ----
        {
            const int er   = tid >> 4;
            const int slot = tid & 15;
            if (slot < 5) {
                const float4 q = *(const float4*)(f_ij + (size_t)(e0 + er) * NRBF + slot * 4);
                const float vals[4] = {q.x, q.y, q.z, q.w};
                #pragma unroll
                for (int u = 0; u < 4; ++u) {
                    const unsigned short hb = f2bf(vals[u]);
                    sA1H[er][slot * 4 + u] = hb;
                    sA1L[er][slot * 4 + u] = f2bf(vals[u] - bf2f(hb));
                }
            } else if (slot < 8) {
                #pragma unroll
                for (int u = 0; u < 4; ++u) {
                    sA1H[er][slot * 4 + u] = 0;
                    sA1L[er][slot * 4 + u] = 0;
                }
            }
            if (tid < 32) {
                sI[tid]  = idx_i[e0 + tid];
                sJ[tid]  = idx_j[e0 + tid];
                sRc[tid] = rcut[e0 + tid];
            }
        }
        __syncthreads();

        // ---- prefetch h[idx_j] gather (overlaps layer-1 MFMA) ----
        float hreg[2][4], rcv[4];
        int jreg[4];
        #pragma unroll
        for (int r = 0; r < 4; ++r) {
            const int row = r0 + quad * 4 + r;
            jreg[r] = sJ[row];
            rcv[r]  = sRc[row];
        }
        #pragma unroll
        for (int ct = 0; ct < 2; ++ct) {
            const int c = cpair * 32 + ct * 16 + l15;
            #pragma unroll
            for (int r = 0; r < 4; ++r)
                hreg[ct][r] = h[(size_t)jreg[r] * 128 + c];
        }

        // ---- layer 1: t = ssp(A1 @ W1 + b1), hi/lo, store t as bf16-hi ----
        {
            const bf16x8 ah = *(const bf16x8*)(&sA1H[r0 + l15][quad * 8]);
            const bf16x8 al = *(const bf16x8*)(&sA1L[r0 + l15][quad * 8]);
            #pragma unroll
            for (int ct = 0; ct < 2; ++ct) {
                f32x4 d = {0.0f, 0.0f, 0.0f, 0.0f};
                d = __builtin_amdgcn_mfma_f32_16x16x32_bf16(ah, w1h[ct], d, 0, 0, 0);
                d = __builtin_amdgcn_mfma_f32_16x16x32_bf16(al, w1h[ct], d, 0, 0, 0);
                d = __builtin_amdgcn_mfma_f32_16x16x32_bf16(ah, w1l[ct], d, 0, 0, 0);
                const int c = cpair * 32 + ct * 16 + l15;
                #pragma unroll
                for (int r = 0; r < 4; ++r) {
                    const float tv = ssp(d[r] + b1r[ct]);
                    sTH[r0 + quad * 4 + r][c] = f2bf(tv);
                }
            }
        }
        __syncthreads();

        // ---- layer 2: Wij = t @ W2 + b2; xij = h[idx_j] * Wij * rcut ----
        {
            bf16x8 ath[4];
            #pragma unroll
            for (int kk = 0; kk < 4; ++kk)
                ath[kk] = *(const bf16x8*)(&sTH[r0 + l15][kk * 32 + quad * 8]);
            #pragma unroll
            for (int ct = 0; ct < 2; ++ct) {
                f32x4 acc = {0.0f, 0.0f, 0.0f, 0.0f};
                #pragma unroll
                for (int kk = 0; kk < 4; ++kk) {
                    acc = __builtin_amdgcn_mfma_f32_16x16x32_bf16(ath[kk], w2h[ct][kk], acc, 0, 0, 0);
                    acc = __builtin_amdgcn_mfma_f32_16x16x32_bf16(ath[kk], w2l[ct][kk], acc, 0, 0, 0);
                }
                const int c = cpair * 32 + ct * 16 + l15;
                #pragma unroll
                for (int r = 0; r < 4; ++r) {
                    const int row = r0 + quad * 4 + r;
                    const float wij = (acc[r] + b2r[ct]) * rcv[r];
                    sXij[row][c] = wij * hreg[ct][r];
                }
            }
        }
        __syncthreads();

        // ---- segmented reduce over sorted idx_i (run-carry across tiles) ----
        #pragma unroll
        for (int r = 0; r < 8; ++r) {
            const int row = qtr * 8 + r;
            const int i = sI[row];
            const float v = sXij[row][col];
            if (i != curI) {
                atomicAdd(&y[(size_t)curI * 128 + col], accV);
                curI = i;
                accV = v;
            } else {
                accV += v;
            }
        }
        __syncthreads();
    }
    atomicAdd(&y[(size_t)curI * 128 + col], accV);
}

// ---------------------------------------------------------------------------
extern "C" void kernel_launch(void* const* d_in, const int* in_sizes, int n_in,
                              void* d_out, int out_size, void* d_ws, size_t ws_size,
                              hipStream_t stream) {
    const float* x      = (const float*)d_in[0];
    const float* f_ij   = (const float*)d_in[1];
    const float* rcut   = (const float*)d_in[2];
    const int*   idx_i  = (const int*)d_in[3];
    const int*   idx_j  = (const int*)d_in[4];
    const float* W_in2f = (const float*)d_in[5];
    const float* W_f1   = (const float*)d_in[6];
    const float* b_f1   = (const float*)d_in[7];
    const float* W_f2   = (const float*)d_in[8];
    const float* b_f2   = (const float*)d_in[9];
    const float* W_o1   = (const float*)d_in[10];
    const float* b_o1   = (const float*)d_in[11];
    const float* W_o2   = (const float*)d_in[12];
    const float* b_o2   = (const float*)d_in[13];

    float* out = (float*)d_out;
    float* h   = (float*)d_ws;   // 25.6 MB; reused as z after cfconv

    hipMemsetAsync(out, 0, (size_t)N_ATOMS * NF * sizeof(float), stream);

    // h = x @ W_in2f
    rowgemm_mfma<false, false><<<512, 512, 0, stream>>>(x, W_in2f, nullptr, h, N_ATOMS);
    // fused filter + cfconv scatter into y (= d_out)
    edge_mfma<<<1536, 512, 0, stream>>>(f_ij, rcut, idx_i, idx_j, h,
                                        W_f1, b_f1, W_f2, b_f2, out);
    // z = ssp(y @ W_o1 + b_o1) -> reuse h region
    rowgemm_mfma<true, true><<<512, 512, 0, stream>>>(out, W_o1, b_o1, h, N_ATOMS);
    // out = z @ W_o2 + b_o2
    rowgemm_mfma<false, true><<<512, 512, 0, stream>>>(h, W_o2, b_o2, out, N_ATOMS);
}

// Round 4
// 837.038 us; speedup vs baseline: 9.8769x; 1.0036x over previous
//
#include <hip/hip_runtime.h>
#include <math.h>

#define N_ATOMS 50000
#define N_EDGES 1600000
#define NRBF 20
#define TILE_E 32
#define N_TILES (N_EDGES / TILE_E)   // 50000 exact

typedef __attribute__((ext_vector_type(8))) short bf16x8;
typedef __attribute__((ext_vector_type(4))) float f32x4;

__device__ __forceinline__ float ssp(float v) {
    // shifted softplus: max(v,0) + ln2*(log2(1+exp2(-|v|*log2e)) - 1)
    const float a = fabsf(v);
    const float e = exp2f(a * -1.4426950408889634f);
    const float l = log2f(1.0f + e);
    return fmaxf(v, 0.0f) + fmaf(l, 0.6931471805599453f, -0.6931471805599453f);
}
__device__ __forceinline__ unsigned short f2bf(float f) {   // fp32 -> bf16 bits, RNE
    unsigned int u = __float_as_uint(f);
    u += 0x7fff + ((u >> 16) & 1);
    return (unsigned short)(u >> 16);
}
__device__ __forceinline__ float bf2f(unsigned short b) {
    return __uint_as_float(((unsigned int)b) << 16);
}

// ---------------------------------------------------------------------------
// MFMA row-GEMM, one 32-row tile per block. A loads issued before W-fragment
// conversion so HBM latency overlaps the conversion VALU work.
template<bool SSP_ACT, bool BIAS>
__global__ __launch_bounds__(512) void rowgemm_mfma(
    const float* __restrict__ A, const float* __restrict__ W,
    const float* __restrict__ bias, float* __restrict__ C, int nrows)
{
    const int tid  = threadIdx.x;
    const int wave = tid >> 6, lane = tid & 63;
    const int l15  = lane & 15, quad = lane >> 4;
    const int rhalf = wave >> 2, cpair = wave & 3;
    const int r0 = rhalf * 16;
    const int rowbase = blockIdx.x * 32;
    const int arow = rowbase + r0 + l15;

    // ---- A raw loads first (in flight during W conversion) ----
    float av[4][8];
    if (arow < nrows) {
        #pragma unroll
        for (int kk = 0; kk < 4; ++kk) {
            const float4 q0 = *(const float4*)(A + (size_t)arow * 128 + kk * 32 + quad * 8);
            const float4 q1 = *(const float4*)(A + (size_t)arow * 128 + kk * 32 + quad * 8 + 4);
            av[kk][0] = q0.x; av[kk][1] = q0.y; av[kk][2] = q0.z; av[kk][3] = q0.w;
            av[kk][4] = q1.x; av[kk][5] = q1.y; av[kk][6] = q1.z; av[kk][7] = q1.w;
        }
    } else {
        #pragma unroll
        for (int kk = 0; kk < 4; ++kk)
            #pragma unroll
            for (int j = 0; j < 8; ++j) av[kk][j] = 0.0f;
    }

    // ---- W fragments (hi/lo) ----
    bf16x8 wh[2][4], wl[2][4];
    float br[2];
    #pragma unroll
    for (int ct = 0; ct < 2; ++ct) {
        const int c = cpair * 32 + ct * 16 + l15;
        br[ct] = BIAS ? bias[c] : 0.0f;
        #pragma unroll
        for (int kk = 0; kk < 4; ++kk) {
            #pragma unroll
            for (int j = 0; j < 8; ++j) {
                const int k = kk * 32 + quad * 8 + j;
                const float v = W[k * 128 + c];
                const unsigned short hb = f2bf(v);
                wh[ct][kk][j] = (short)hb;
                wl[ct][kk][j] = (short)f2bf(v - bf2f(hb));
            }
        }
    }

    // ---- A hi/lo conversion ----
    bf16x8 ah[4], al[4];
    #pragma unroll
    for (int kk = 0; kk < 4; ++kk) {
        #pragma unroll
        for (int j = 0; j < 8; ++j) {
            const unsigned short hb = f2bf(av[kk][j]);
            ah[kk][j] = (short)hb;
            al[kk][j] = (short)f2bf(av[kk][j] - bf2f(hb));
        }
    }

    #pragma unroll
    for (int ct = 0; ct < 2; ++ct) {
        f32x4 acc = {0.0f, 0.0f, 0.0f, 0.0f};
        #pragma unroll
        for (int kk = 0; kk < 4; ++kk) {
            acc = __builtin_amdgcn_mfma_f32_16x16x32_bf16(ah[kk], wh[ct][kk], acc, 0, 0, 0);
            acc = __builtin_amdgcn_mfma_f32_16x16x32_bf16(al[kk], wh[ct][kk], acc, 0, 0, 0);
            acc = __builtin_amdgcn_mfma_f32_16x16x32_bf16(ah[kk], wl[ct][kk], acc, 0, 0, 0);
        }
        const int c = cpair * 32 + ct * 16 + l15;
        #pragma unroll
        for (int r = 0; r < 4; ++r) {
            const int row = rowbase + r0 + quad * 4 + r;
            if (row < nrows) {
                float v = acc[r] + br[ct];
                if (SSP_ACT) v = ssp(v);
                C[(size_t)row * 128 + c] = v;
            }
        }
    }
}

// ---------------------------------------------------------------------------
// Fused edge kernel, software-pipelined:
//   - f_ij staging double-buffered (parity p); tile t+1 prefetched to regs
//     right after B1(t), written to LDS[p^1] after B3(t).
//   - h[idx_j] gather for t+1: idx_j issued after B1(t), h issued after B3(t),
//     consumed in layer2(t+1).
//   - idx_i / rcut read directly from global (L1 broadcast), no LDS staging.
//   - xij staged transposed (sXT[col][row]) -> b128 LDS writes/reads.
// 3 barriers per tile.
__global__ __launch_bounds__(512, 2) void edge_mfma(
    const float* __restrict__ f_ij, const float* __restrict__ rcut,
    const int* __restrict__ idx_i, const int* __restrict__ idx_j,
    const float* __restrict__ h,
    const float* __restrict__ W1, const float* __restrict__ b1,
    const float* __restrict__ W2, const float* __restrict__ b2,
    float* __restrict__ y)
{
    __shared__ unsigned short sA1H[2][32][40], sA1L[2][32][40];  // f_ij hi/lo, double-buffered
    __shared__ unsigned short sTH[32][136];                       // t (bf16 hi)
    __shared__ float sXT[128][36];                                // xij transposed [col][row]

    const int tid  = threadIdx.x;
    const int wave = tid >> 6, lane = tid & 63;
    const int l15  = lane & 15, quad = lane >> 4;
    const int rhalf = wave >> 2, cpair = wave & 3;
    const int r0 = rhalf * 16;

    // ---- weight fragments (one-time) ----
    bf16x8 w1h[2], w1l[2];
    bf16x8 w2h[2][4], w2l[2][4];
    float b1r[2], b2r[2];
    #pragma unroll
    for (int ct = 0; ct < 2; ++ct) {
        const int c = cpair * 32 + ct * 16 + l15;
        b1r[ct] = b1[c];
        b2r[ct] = b2[c];
        #pragma unroll
        for (int j = 0; j < 8; ++j) {
            const int k = quad * 8 + j;
            const float v = (k < NRBF) ? W1[k * 128 + c] : 0.0f;
            const unsigned short hb = f2bf(v);
            w1h[ct][j] = (short)hb;
            w1l[ct][j] = (short)f2bf(v - bf2f(hb));
        }
        #pragma unroll
        for (int kk = 0; kk < 4; ++kk) {
            #pragma unroll
            for (int j = 0; j < 8; ++j) {
                const int k = kk * 32 + quad * 8 + j;
                const float v = W2[k * 128 + c];
                const unsigned short hb = f2bf(v);
                w2h[ct][kk][j] = (short)hb;
                w2l[ct][kk][j] = (short)f2bf(v - bf2f(hb));
            }
        }
    }

    // ---- zero the K-pad (cols 20..31) of both staging buffers, once ----
    for (int i = tid; i < 2 * 32 * 12; i += 512) {
        const int buf = i / 384, row = (i % 384) / 12, cc = 20 + (i % 12);
        sA1H[buf][row][cc] = 0;
        sA1L[buf][row][cc] = 0;
    }

    const int nb = gridDim.x;
    const int t0 = (int)(((long long)blockIdx.x * N_TILES) / nb);
    const int t1 = (int)(((long long)(blockIdx.x + 1) * N_TILES) / nb);

    const int er = tid >> 4, slot = tid & 15;
    const bool loader = (slot < 5);
    const int col = tid & 127, qtr = tid >> 7;

    // ---- preloop: stage tile t0 + its gather ----
    {
        const int e0 = t0 * TILE_E;
        if (loader) {
            const float4 q = *(const float4*)(f_ij + (size_t)(e0 + er) * NRBF + slot * 4);
            const float vals[4] = {q.x, q.y, q.z, q.w};
            #pragma unroll
            for (int u = 0; u < 4; ++u) {
                const unsigned short hb = f2bf(vals[u]);
                sA1H[0][er][slot * 4 + u] = hb;
                sA1L[0][er][slot * 4 + u] = f2bf(vals[u] - bf2f(hb));
            }
        }
    }
    float rcn[4], hn[2][4];
    {
        const int e0 = t0 * TILE_E;
        int j0[4];
        #pragma unroll
        for (int r = 0; r < 4; ++r) {
            const int row = r0 + quad * 4 + r;
            j0[r]  = idx_j[e0 + row];
            rcn[r] = rcut[e0 + row];
        }
        #pragma unroll
        for (int ct = 0; ct < 2; ++ct) {
            const int c = cpair * 32 + ct * 16 + l15;
            #pragma unroll
            for (int r = 0; r < 4; ++r)
                hn[ct][r] = h[(size_t)j0[r] * 128 + c];
        }
    }
    int curI = idx_i[(size_t)t0 * TILE_E];
    float accV = 0.0f;

    int p = 0;
    for (int t = t0; t < t1; ++t, p ^= 1) {
        const int e0 = t * TILE_E;
        const bool hasnext = (t + 1 < t1);
        __syncthreads();   // B1: staging[p] visible; sXT/sTH free

        // prefetch: next f_ij -> regs; next idx_j; this tile's idx_i (reduce)
        float4 pfn;
        if (hasnext && loader)
            pfn = *(const float4*)(f_ij + (size_t)(e0 + TILE_E + er) * NRBF + slot * 4);
        int jn2[4];
        if (hasnext) {
            #pragma unroll
            for (int r = 0; r < 4; ++r)
                jn2[r] = idx_j[e0 + TILE_E + r0 + quad * 4 + r];
        }
        int iir[8];
        #pragma unroll
        for (int r = 0; r < 8; ++r) iir[r] = idx_i[e0 + qtr * 8 + r];

        // ---- layer 1: t = ssp(A1 @ W1 + b1), hi/lo ----
        {
            const bf16x8 ah = *(const bf16x8*)(&sA1H[p][r0 + l15][quad * 8]);
            const bf16x8 al = *(const bf16x8*)(&sA1L[p][r0 + l15][quad * 8]);
            #pragma unroll
            for (int ct = 0; ct < 2; ++ct) {
                f32x4 d = {0.0f, 0.0f, 0.0f, 0.0f};
                d = __builtin_amdgcn_mfma_f32_16x16x32_bf16(ah, w1h[ct], d, 0, 0, 0);
                d = __builtin_amdgcn_mfma_f32_16x16x32_bf16(al, w1h[ct], d, 0, 0, 0);
                d = __builtin_amdgcn_mfma_f32_16x16x32_bf16(ah, w1l[ct], d, 0, 0, 0);
                const int c = cpair * 32 + ct * 16 + l15;
                #pragma unroll
                for (int r = 0; r < 4; ++r)
                    sTH[r0 + quad * 4 + r][c] = f2bf(ssp(d[r] + b1r[ct]));
            }
        }
        __syncthreads();   // B2: sTH visible

        // ---- layer 2: Wij = t @ W2 + b2; xij = h * Wij * rcut -> sXT ----
        {
            bf16x8 ath[4];
            #pragma unroll
            for (int kk = 0; kk < 4; ++kk)
                ath[kk] = *(const bf16x8*)(&sTH[r0 + l15][kk * 32 + quad * 8]);
            #pragma unroll
            for (int ct = 0; ct < 2; ++ct) {
                f32x4 acc = {0.0f, 0.0f, 0.0f, 0.0f};
                #pragma unroll
                for (int kk = 0; kk < 4; ++kk) {
                    acc = __builtin_amdgcn_mfma_f32_16x16x32_bf16(ath[kk], w2h[ct][kk], acc, 0, 0, 0);
                    acc = __builtin_amdgcn_mfma_f32_16x16x32_bf16(ath[kk], w2l[ct][kk], acc, 0, 0, 0);
                }
                const int c = cpair * 32 + ct * 16 + l15;
                float4 xv;
                xv.x = (acc[0] + b2r[ct]) * rcn[0] * hn[ct][0];
                xv.y = (acc[1] + b2r[ct]) * rcn[1] * hn[ct][1];
                xv.z = (acc[2] + b2r[ct]) * rcn[2] * hn[ct][2];
                xv.w = (acc[3] + b2r[ct]) * rcn[3] * hn[ct][3];
                *(float4*)(&sXT[c][r0 + quad * 4]) = xv;
            }
        }
        __syncthreads();   // B3: sXT visible; sA1[p] consumed

        // ---- stage t+1 (LDS write + gather issue) ----
        if (hasnext) {
            if (loader) {
                const float vals[4] = {pfn.x, pfn.y, pfn.z, pfn.w};
                #pragma unroll
                for (int u = 0; u < 4; ++u) {
                    const unsigned short hb = f2bf(vals[u]);
                    sA1H[p ^ 1][er][slot * 4 + u] = hb;
                    sA1L[p ^ 1][er][slot * 4 + u] = f2bf(vals[u] - bf2f(hb));
                }
            }
            const int e0n = e0 + TILE_E;
            #pragma unroll
            for (int r = 0; r < 4; ++r)
                rcn[r] = rcut[e0n + r0 + quad * 4 + r];
            #pragma unroll
            for (int ct = 0; ct < 2; ++ct) {
                const int c = cpair * 32 + ct * 16 + l15;
                #pragma unroll
                for (int r = 0; r < 4; ++r)
                    hn[ct][r] = h[(size_t)jn2[r] * 128 + c];
            }
        }

        // ---- segmented reduce (sorted idx_i, run-carry across tiles) ----
        const f32x4 x0 = *(const f32x4*)(&sXT[col][qtr * 8]);
        const f32x4 x1 = *(const f32x4*)(&sXT[col][qtr * 8 + 4]);
        #pragma unroll
        for (int r = 0; r < 8; ++r) {
            const float v = (r < 4) ? x0[r] : x1[r - 4];
            if (iir[r] != curI) {
                atomicAdd(&y[(size_t)curI * 128 + col], accV);
                curI = iir[r];
                accV = v;
            } else {
                accV += v;
            }
        }
    }
    atomicAdd(&y[(size_t)curI * 128 + col], accV);
}

// ---------------------------------------------------------------------------
extern "C" void kernel_launch(void* const* d_in, const int* in_sizes, int n_in,
                              void* d_out, int out_size, void* d_ws, size_t ws_size,
                              hipStream_t stream) {
    const float* x      = (const float*)d_in[0];
    const float* f_ij   = (const float*)d_in[1];
    const float* rcut   = (const float*)d_in[2];
    const int*   idx_i  = (const int*)d_in[3];
    const int*   idx_j  = (const int*)d_in[4];
    const float* W_in2f = (const float*)d_in[5];
    const float* W_f1   = (const float*)d_in[6];
    const float* b_f1   = (const float*)d_in[7];
    const float* W_f2   = (const float*)d_in[8];
    const float* b_f2   = (const float*)d_in[9];
    const float* W_o1   = (const float*)d_in[10];
    const float* b_o1   = (const float*)d_in[11];
    const float* W_o2   = (const float*)d_in[12];
    const float* b_o2   = (const float*)d_in[13];

    float* out = (float*)d_out;
    float* h   = (float*)d_ws;   // 25.6 MB; reused as z after cfconv

    hipMemsetAsync(out, 0, (size_t)N_ATOMS * 128 * sizeof(float), stream);

    const int ntiles = (N_ATOMS + 31) / 32;   // 1563
    // h = x @ W_in2f
    rowgemm_mfma<false, false><<<ntiles, 512, 0, stream>>>(x, W_in2f, nullptr, h, N_ATOMS);
    // fused filter + cfconv scatter into y (= d_out)
    edge_mfma<<<1024, 512, 0, stream>>>(f_ij, rcut, idx_i, idx_j, h,
                                        W_f1, b_f1, W_f2, b_f2, out);
    // z = ssp(y @ W_o1 + b_o1) -> reuse h region
    rowgemm_mfma<true, true><<<ntiles, 512, 0, stream>>>(out, W_o1, b_o1, h, N_ATOMS);
    // out = z @ W_o2 + b_o2
    rowgemm_mfma<false, true><<<ntiles, 512, 0, stream>>>(h, W_o2, b_o2, out, N_ATOMS);
}